// Round 1
// baseline (111.715 us; speedup 1.0000x reference)
//
#include <hip/hip_runtime.h>
#include <math.h>

#define NB 4
#define NS 512
#define NV 32000
#define NROWS (NB * NS)
#define KL_ALPHA 0.3f

__device__ __forceinline__ void merge2(float& m, float& s, float om, float os) {
    float nm = fmaxf(m, om);
    s = s * __expf(m - nm) + os * __expf(om - nm);
    m = nm;
}
__device__ __forceinline__ void merge3(float& m, float& s, float& t, float om, float os, float ot) {
    float nm = fmaxf(m, om);
    float ea = __expf(m - nm), eb = __expf(om - nm);
    s = s * ea + os * eb;
    t = t * ea + ot * eb;
    m = nm;
}

// Kernel A: per-row (b,s) online-softmax stats for logits (x) and ref_logits (y),
// plus KL weighted sum and the 3 per-row gathers. One block per row.
__global__ __launch_bounds__(256) void krow(const float* __restrict__ logits,
                                            const float* __restrict__ ref_logits,
                                            const int* __restrict__ input_ids,
                                            float* __restrict__ logZx,
                                            float* __restrict__ logZy,
                                            float* __restrict__ klrow,
                                            float* __restrict__ surp,
                                            float* __restrict__ gval,
                                            float* __restrict__ grval) {
    const int row = blockIdx.x;             // 0..NROWS-1
    const int b = row / NS, s = row - b * NS;
    const size_t base = (size_t)(b * (NS + 1) + s) * NV;
    const float4* __restrict__ x4 = (const float4*)(logits + base);
    const float4* __restrict__ y4 = (const float4*)(ref_logits + base);
    const int tid = threadIdx.x;

    // 4 independent online-softmax accumulator sets (one per float4 lane) for ILP
    float mx[4], sx[4], my[4], sy[4], ty[4];
#pragma unroll
    for (int j = 0; j < 4; ++j) { mx[j] = -INFINITY; sx[j] = 0.f; my[j] = -INFINITY; sy[j] = 0.f; ty[j] = 0.f; }

    for (int i = tid; i < NV / 4; i += 256) {
        float4 xv = x4[i];
        float4 yv = y4[i];
        float xs[4] = {xv.x, xv.y, xv.z, xv.w};
        float ys[4] = {yv.x, yv.y, yv.z, yv.w};
#pragma unroll
        for (int j = 0; j < 4; ++j) {
            float xe = xs[j], ye = ys[j];
            float nmx = fmaxf(mx[j], xe);
            sx[j] = sx[j] * __expf(mx[j] - nmx) + __expf(xe - nmx);
            mx[j] = nmx;
            float nmy = fmaxf(my[j], ye);
            float a = __expf(my[j] - nmy);
            float e = __expf(ye - nmy);
            sy[j] = sy[j] * a + e;
            ty[j] = ty[j] * a + e * (ye - xe);
            my[j] = nmy;
        }
    }
    // merge the 4 lanes (all finite: each set saw >= 31 elements)
    float Mx = mx[0], Sx = sx[0];
    float My = my[0], Sy = sy[0], Ty = ty[0];
#pragma unroll
    for (int j = 1; j < 4; ++j) {
        merge2(Mx, Sx, mx[j], sx[j]);
        merge3(My, Sy, Ty, my[j], sy[j], ty[j]);
    }
    // wave (64-lane) butterfly reduce
    for (int off = 32; off > 0; off >>= 1) {
        float oMx = __shfl_xor(Mx, off);
        float oSx = __shfl_xor(Sx, off);
        merge2(Mx, Sx, oMx, oSx);
        float oMy = __shfl_xor(My, off);
        float oSy = __shfl_xor(Sy, off);
        float oTy = __shfl_xor(Ty, off);
        merge3(My, Sy, Ty, oMy, oSy, oTy);
    }
    __shared__ float red[4][5];
    const int wave = tid >> 6, lane = tid & 63;
    if (lane == 0) {
        red[wave][0] = Mx; red[wave][1] = Sx;
        red[wave][2] = My; red[wave][3] = Sy; red[wave][4] = Ty;
    }
    __syncthreads();
    if (tid == 0) {
        for (int w = 1; w < 4; ++w) {
            merge2(Mx, Sx, red[w][0], red[w][1]);
            merge3(My, Sy, Ty, red[w][2], red[w][3], red[w][4]);
        }
        float lzx = Mx + __logf(Sx);
        float lzy = My + __logf(Sy);
        logZx[row] = lzx;
        logZy[row] = lzy;
        // KL row: sum p_ref*(y-x) + logZx - logZy
        klrow[row] = Ty / Sy + lzx - lzy;
        // surprisal[b,s] = -(x[id0] - logZx)
        int id0 = input_ids[b * NS + s];
        surp[row] = lzx - logits[base + id0];
        if (s < NS - 1) {
            int id1 = input_ids[b * NS + s + 1];
            gval[row]  = logits[base + id1] - lzx;
            grval[row] = ref_logits[base + id1] - lzy;
        } else {
            gval[row] = 0.f;
            grval[row] = 0.f;
        }
    }
}

// Kernel B: single block finalize — scatter-add summed_surprisal, preds, all scalars.
__global__ __launch_bounds__(1024) void kfinal(const int* __restrict__ input_ids,
                                               const int* __restrict__ attention_mask,
                                               const int* __restrict__ word_ids,
                                               const int* __restrict__ word_lengths,
                                               const float* __restrict__ lufreq,
                                               const float* __restrict__ labels,
                                               const float* __restrict__ W_head,
                                               const float* __restrict__ b_head,
                                               const float* __restrict__ logZx,
                                               const float* __restrict__ logZy,
                                               const float* __restrict__ klrow,
                                               const float* __restrict__ surp,
                                               const float* __restrict__ gval,
                                               const float* __restrict__ grval,
                                               float* __restrict__ out) {
    __shared__ float summed[NROWS];   // 8 KB: summed_surprisal (B,S)
    const int tid = threadIdx.x;
    for (int p = tid; p < NROWS; p += 1024) summed[p] = 0.f;
    __syncthreads();
    // scatter-add masked surprisal into word buckets
    for (int p = tid; p < NROWS; p += 1024) {
        int b = p / NS;
        int wid = word_ids[p];
        if (wid >= 0 && wid < NS) atomicAdd(&summed[b * NS + wid], surp[p]);
    }
    __syncthreads();

    const float W0 = W_head[0], W1 = W_head[1], W2 = W_head[2], bh = b_head[0];
    float mse_n = 0.f, mse_d = 0.f, kl_n = 0.f, kl_d = 0.f;
    float g_n = 0.f, gr_n = 0.f, g_d = 0.f;
    for (int p = tid; p < NROWS; p += 1024) {
        int b = p / NS, s = p - b * NS;
        int wid = word_ids[p];
        bool valid = (wid >= 0) && (wid < NS);
        int safe = wid < 0 ? 0 : (wid > NS - 1 ? NS - 1 : wid);
        int lens = word_lengths[b * NS + safe];
        valid = valid && (lens != -1);
        float el = valid ? (float)lens : 0.f;
        float ef = valid ? lufreq[b * NS + safe] : 0.f;
        float pred = summed[p] * W0 + el * W1 + ef * W2 + bh;
        out[1 + p] = pred;
        float lab = labels[p];
        float mw = (lab != -1.0f) ? 1.f : 0.f;
        float diff = lab - pred;
        mse_n += diff * diff * mw;
        mse_d += mw;
        // kl_mask[b,s] = 0 if s==0 else (word_ids[b,s-1] != -1)
        float km = (s == 0) ? 0.f : ((word_ids[p - 1] != -1) ? 1.f : 0.f);
        kl_n += klrow[p] * km;
        kl_d += km;
        if (s < NS - 1) {
            float am = (float)attention_mask[b * NS + s + 1];
            g_n += gval[p] * am;
            gr_n += grval[p] * am;
            g_d += am;
        }
    }
    // block reduce of 7 accumulators
    for (int off = 32; off > 0; off >>= 1) {
        mse_n += __shfl_xor(mse_n, off);
        mse_d += __shfl_xor(mse_d, off);
        kl_n  += __shfl_xor(kl_n, off);
        kl_d  += __shfl_xor(kl_d, off);
        g_n   += __shfl_xor(g_n, off);
        gr_n  += __shfl_xor(gr_n, off);
        g_d   += __shfl_xor(g_d, off);
    }
    __shared__ float r2[16][7];
    const int wave = tid >> 6, lane = tid & 63;
    if (lane == 0) {
        r2[wave][0] = mse_n; r2[wave][1] = mse_d;
        r2[wave][2] = kl_n;  r2[wave][3] = kl_d;
        r2[wave][4] = g_n;   r2[wave][5] = gr_n; r2[wave][6] = g_d;
    }
    __syncthreads();
    if (tid == 0) {
        float a0 = 0, a1 = 0, a2 = 0, a3 = 0, a4 = 0, a5 = 0, a6 = 0;
        for (int w = 0; w < 16; ++w) {
            a0 += r2[w][0]; a1 += r2[w][1]; a2 += r2[w][2]; a3 += r2[w][3];
            a4 += r2[w][4]; a5 += r2[w][5]; a6 += r2[w][6];
        }
        float mse = a0 / a1;
        float kl = a2 / a3;
        float loss = mse + KL_ALPHA * kl;   // MSE_WEIGHT = 1
        float avg = a4 / a6;
        float delta = avg - a5 / a6;
        out[0] = loss;
        out[1 + NROWS] = mse;
        out[2 + NROWS] = kl;
        out[3 + NROWS] = avg;
        out[4 + NROWS] = delta;
    }
}

extern "C" void kernel_launch(void* const* d_in, const int* in_sizes, int n_in,
                              void* d_out, int out_size, void* d_ws, size_t ws_size,
                              hipStream_t stream) {
    const float* logits        = (const float*)d_in[0];
    const float* ref_logits    = (const float*)d_in[1];
    const int*   input_ids     = (const int*)d_in[2];
    const int*   attention_mask= (const int*)d_in[3];
    const int*   word_ids      = (const int*)d_in[4];
    const int*   word_lengths  = (const int*)d_in[5];
    const float* lufreq        = (const float*)d_in[6];
    const float* labels        = (const float*)d_in[7];
    const float* W_head        = (const float*)d_in[8];
    const float* b_head        = (const float*)d_in[9];
    float* out = (float*)d_out;
    float* ws = (float*)d_ws;

    float* logZx = ws;
    float* logZy = ws + NROWS;
    float* klrow = ws + 2 * NROWS;
    float* surp  = ws + 3 * NROWS;
    float* gvals = ws + 4 * NROWS;
    float* grvals= ws + 5 * NROWS;

    hipLaunchKernelGGL(krow, dim3(NROWS), dim3(256), 0, stream,
                       logits, ref_logits, input_ids,
                       logZx, logZy, klrow, surp, gvals, grvals);
    hipLaunchKernelGGL(kfinal, dim3(1), dim3(1024), 0, stream,
                       input_ids, attention_mask, word_ids, word_lengths,
                       lufreq, labels, W_head, b_head,
                       logZx, logZy, klrow, surp, gvals, grvals, out);
}

// Round 2
// 109.969 us; speedup vs baseline: 1.0159x; 1.0159x over previous
//
#include <hip/hip_runtime.h>
#include <math.h>

#define NB 4
#define NS 512
#define NV 32000
#define NROWS (NB * NS)
#define KL_ALPHA 0.3f
#define SAFE_MAX 60.0f

// Kernel A: per-row (b,s) softmax stats for logits (x) and ref_logits (y),
// plus KL weighted sum and the 3 per-row gathers. One block per row.
// Fast path: direct exp-sum (valid while row max < SAFE_MAX, always true for
// this data); guarded max-shifted second pass otherwise.
__global__ __launch_bounds__(256) void krow(const float* __restrict__ logits,
                                            const float* __restrict__ ref_logits,
                                            const int* __restrict__ input_ids,
                                            float* __restrict__ logZx,
                                            float* __restrict__ logZy,
                                            float* __restrict__ klrow,
                                            float* __restrict__ surp,
                                            float* __restrict__ gval,
                                            float* __restrict__ grval) {
    const int row = blockIdx.x;             // 0..NROWS-1
    const int b = row / NS, s = row - b * NS;
    const size_t base = (size_t)(b * (NS + 1) + s) * NV;
    const float4* __restrict__ x4 = (const float4*)(logits + base);
    const float4* __restrict__ y4 = (const float4*)(ref_logits + base);
    const int tid = threadIdx.x;

    // independent accumulator chains (pure adds — no serial exp recurrence)
    float sx[4] = {0.f, 0.f, 0.f, 0.f};
    float sy[4] = {0.f, 0.f, 0.f, 0.f};
    float ty[4] = {0.f, 0.f, 0.f, 0.f};
    float mx = -INFINITY, my = -INFINITY;

    for (int i = tid; i < NV / 4; i += 256) {
        float4 xv = x4[i];
        float4 yv = y4[i];
        float xs[4] = {xv.x, xv.y, xv.z, xv.w};
        float ys[4] = {yv.x, yv.y, yv.z, yv.w};
#pragma unroll
        for (int j = 0; j < 4; ++j) {
            float xe = xs[j], ye = ys[j];
            mx = fmaxf(mx, xe);
            my = fmaxf(my, ye);
            float ex = __expf(xe);
            float ey = __expf(ye);
            sx[j] += ex;
            sy[j] += ey;
            ty[j] = fmaf(ey, ye - xe, ty[j]);
        }
    }
    float Sx = (sx[0] + sx[1]) + (sx[2] + sx[3]);
    float Sy = (sy[0] + sy[1]) + (sy[2] + sy[3]);
    float Ty = (ty[0] + ty[1]) + (ty[2] + ty[3]);

    // wave butterfly reduce (64 lanes)
    for (int off = 32; off > 0; off >>= 1) {
        Sx += __shfl_xor(Sx, off);
        Sy += __shfl_xor(Sy, off);
        Ty += __shfl_xor(Ty, off);
        mx = fmaxf(mx, __shfl_xor(mx, off));
        my = fmaxf(my, __shfl_xor(my, off));
    }
    __shared__ float red[4][5];
    const int wave = tid >> 6, lane = tid & 63;
    if (lane == 0) {
        red[wave][0] = Sx; red[wave][1] = Sy; red[wave][2] = Ty;
        red[wave][3] = mx; red[wave][4] = my;
    }
    __syncthreads();
    // every thread computes the block totals (needed for fallback decision)
    float tSx = 0.f, tSy = 0.f, tTy = 0.f, tMx = -INFINITY, tMy = -INFINITY;
#pragma unroll
    for (int w = 0; w < 4; ++w) {
        tSx += red[w][0];
        tSy += red[w][1];
        tTy += red[w][2];
        tMx = fmaxf(tMx, red[w][3]);
        tMy = fmaxf(tMy, red[w][4]);
    }

    float lzx, lzy, klv;
    if (tMx < SAFE_MAX && tMy < SAFE_MAX) {
        // fast path: sums are exact in fp32 range
        lzx = __logf(tSx);
        lzy = __logf(tSy);
        klv = tTy / tSy + lzx - lzy;
    } else {
        // rare fallback: max-shifted second pass (data is L2-warm)
        float fsx = 0.f, fsy = 0.f, fty = 0.f;
        for (int i = tid; i < NV / 4; i += 256) {
            float4 xv = x4[i];
            float4 yv = y4[i];
            float xs[4] = {xv.x, xv.y, xv.z, xv.w};
            float ys[4] = {yv.x, yv.y, yv.z, yv.w};
#pragma unroll
            for (int j = 0; j < 4; ++j) {
                float xe = xs[j], ye = ys[j];
                fsx += __expf(xe - tMx);
                float ey = __expf(ye - tMy);
                fsy += ey;
                fty = fmaf(ey, ye - xe, fty);
            }
        }
        for (int off = 32; off > 0; off >>= 1) {
            fsx += __shfl_xor(fsx, off);
            fsy += __shfl_xor(fsy, off);
            fty += __shfl_xor(fty, off);
        }
        __syncthreads();
        if (lane == 0) { red[wave][0] = fsx; red[wave][1] = fsy; red[wave][2] = fty; }
        __syncthreads();
        float gSx = 0.f, gSy = 0.f, gTy = 0.f;
#pragma unroll
        for (int w = 0; w < 4; ++w) { gSx += red[w][0]; gSy += red[w][1]; gTy += red[w][2]; }
        lzx = tMx + __logf(gSx);
        lzy = tMy + __logf(gSy);
        klv = gTy / gSy + lzx - lzy;
    }

    if (tid == 0) {
        logZx[row] = lzx;
        logZy[row] = lzy;
        klrow[row] = klv;
        int id0 = input_ids[b * NS + s];
        surp[row] = lzx - logits[base + id0];
        if (s < NS - 1) {
            int id1 = input_ids[b * NS + s + 1];
            gval[row]  = logits[base + id1] - lzx;
            grval[row] = ref_logits[base + id1] - lzy;
        } else {
            gval[row] = 0.f;
            grval[row] = 0.f;
        }
    }
}

// Kernel B: single block finalize — scatter-add summed_surprisal, preds, all scalars.
__global__ __launch_bounds__(1024) void kfinal(const int* __restrict__ input_ids,
                                               const int* __restrict__ attention_mask,
                                               const int* __restrict__ word_ids,
                                               const int* __restrict__ word_lengths,
                                               const float* __restrict__ lufreq,
                                               const float* __restrict__ labels,
                                               const float* __restrict__ W_head,
                                               const float* __restrict__ b_head,
                                               const float* __restrict__ logZx,
                                               const float* __restrict__ logZy,
                                               const float* __restrict__ klrow,
                                               const float* __restrict__ surp,
                                               const float* __restrict__ gval,
                                               const float* __restrict__ grval,
                                               float* __restrict__ out) {
    __shared__ float summed[NROWS];   // 8 KB: summed_surprisal (B,S)
    const int tid = threadIdx.x;
    for (int p = tid; p < NROWS; p += 1024) summed[p] = 0.f;
    __syncthreads();
    for (int p = tid; p < NROWS; p += 1024) {
        int b = p / NS;
        int wid = word_ids[p];
        if (wid >= 0 && wid < NS) atomicAdd(&summed[b * NS + wid], surp[p]);
    }
    __syncthreads();

    const float W0 = W_head[0], W1 = W_head[1], W2 = W_head[2], bh = b_head[0];
    float mse_n = 0.f, mse_d = 0.f, kl_n = 0.f, kl_d = 0.f;
    float g_n = 0.f, gr_n = 0.f, g_d = 0.f;
    for (int p = tid; p < NROWS; p += 1024) {
        int b = p / NS, s = p - b * NS;
        int wid = word_ids[p];
        bool valid = (wid >= 0) && (wid < NS);
        int safe = wid < 0 ? 0 : (wid > NS - 1 ? NS - 1 : wid);
        int lens = word_lengths[b * NS + safe];
        valid = valid && (lens != -1);
        float el = valid ? (float)lens : 0.f;
        float ef = valid ? lufreq[b * NS + safe] : 0.f;
        float pred = summed[p] * W0 + el * W1 + ef * W2 + bh;
        out[1 + p] = pred;
        float lab = labels[p];
        float mw = (lab != -1.0f) ? 1.f : 0.f;
        float diff = lab - pred;
        mse_n += diff * diff * mw;
        mse_d += mw;
        float km = (s == 0) ? 0.f : ((word_ids[p - 1] != -1) ? 1.f : 0.f);
        kl_n += klrow[p] * km;
        kl_d += km;
        if (s < NS - 1) {
            float am = (float)attention_mask[b * NS + s + 1];
            g_n += gval[p] * am;
            gr_n += grval[p] * am;
            g_d += am;
        }
    }
    for (int off = 32; off > 0; off >>= 1) {
        mse_n += __shfl_xor(mse_n, off);
        mse_d += __shfl_xor(mse_d, off);
        kl_n  += __shfl_xor(kl_n, off);
        kl_d  += __shfl_xor(kl_d, off);
        g_n   += __shfl_xor(g_n, off);
        gr_n  += __shfl_xor(gr_n, off);
        g_d   += __shfl_xor(g_d, off);
    }
    __shared__ float r2[16][7];
    const int wave = tid >> 6, lane = tid & 63;
    if (lane == 0) {
        r2[wave][0] = mse_n; r2[wave][1] = mse_d;
        r2[wave][2] = kl_n;  r2[wave][3] = kl_d;
        r2[wave][4] = g_n;   r2[wave][5] = gr_n; r2[wave][6] = g_d;
    }
    __syncthreads();
    if (tid == 0) {
        float a0 = 0, a1 = 0, a2 = 0, a3 = 0, a4 = 0, a5 = 0, a6 = 0;
        for (int w = 0; w < 16; ++w) {
            a0 += r2[w][0]; a1 += r2[w][1]; a2 += r2[w][2]; a3 += r2[w][3];
            a4 += r2[w][4]; a5 += r2[w][5]; a6 += r2[w][6];
        }
        float mse = a0 / a1;
        float kl = a2 / a3;
        float loss = mse + KL_ALPHA * kl;   // MSE_WEIGHT = 1
        float avg = a4 / a6;
        float delta = avg - a5 / a6;
        out[0] = loss;
        out[1 + NROWS] = mse;
        out[2 + NROWS] = kl;
        out[3 + NROWS] = avg;
        out[4 + NROWS] = delta;
    }
}

extern "C" void kernel_launch(void* const* d_in, const int* in_sizes, int n_in,
                              void* d_out, int out_size, void* d_ws, size_t ws_size,
                              hipStream_t stream) {
    const float* logits        = (const float*)d_in[0];
    const float* ref_logits    = (const float*)d_in[1];
    const int*   input_ids     = (const int*)d_in[2];
    const int*   attention_mask= (const int*)d_in[3];
    const int*   word_ids      = (const int*)d_in[4];
    const int*   word_lengths  = (const int*)d_in[5];
    const float* lufreq        = (const float*)d_in[6];
    const float* labels        = (const float*)d_in[7];
    const float* W_head        = (const float*)d_in[8];
    const float* b_head        = (const float*)d_in[9];
    float* out = (float*)d_out;
    float* ws = (float*)d_ws;

    float* logZx = ws;
    float* logZy = ws + NROWS;
    float* klrow = ws + 2 * NROWS;
    float* surp  = ws + 3 * NROWS;
    float* gvals = ws + 4 * NROWS;
    float* grvals= ws + 5 * NROWS;

    hipLaunchKernelGGL(krow, dim3(NROWS), dim3(256), 0, stream,
                       logits, ref_logits, input_ids,
                       logZx, logZy, klrow, surp, gvals, grvals);
    hipLaunchKernelGGL(kfinal, dim3(1), dim3(1024), 0, stream,
                       input_ids, attention_mask, word_ids, word_lengths,
                       lufreq, labels, W_head, b_head,
                       logZx, logZy, klrow, surp, gvals, grvals, out);
}

// Round 3
// 107.951 us; speedup vs baseline: 1.0349x; 1.0187x over previous
//
#include <hip/hip_runtime.h>
#include <math.h>

#define NB 4
#define NS 512
#define NV 32000
#define NROWS (NB * NS)
#define KL_ALPHA 0.3f
#define SAFE_MAX 60.0f

// per-element accumulation: sums of exp(x), exp(y), exp(y)*(y-x), plus maxes
__device__ __forceinline__ void proc4(const float4& xv, const float4& yv,
                                      float* __restrict__ sx, float* __restrict__ sy,
                                      float* __restrict__ ty, float& mx, float& my) {
    float xs[4] = {xv.x, xv.y, xv.z, xv.w};
    float ys[4] = {yv.x, yv.y, yv.z, yv.w};
#pragma unroll
    for (int j = 0; j < 4; ++j) {
        float xe = xs[j], ye = ys[j];
        mx = fmaxf(mx, xe);
        my = fmaxf(my, ye);
        float ex = __expf(xe);
        float ey = __expf(ye);
        sx[j] += ex;
        sy[j] += ey;
        ty[j] = fmaf(ey, ye - xe, ty[j]);
    }
}

// Kernel A: per-row (b,s) softmax stats for logits (x) and ref_logits (y),
// one block per row, depth-2 software-pipelined streaming loads.
__global__ __launch_bounds__(256) void krow(const float* __restrict__ logits,
                                            const float* __restrict__ ref_logits,
                                            const int* __restrict__ input_ids,
                                            float* __restrict__ logZx,
                                            float* __restrict__ logZy,
                                            float* __restrict__ klrow,
                                            float* __restrict__ surp,
                                            float* __restrict__ gval,
                                            float* __restrict__ grval) {
    const int row = blockIdx.x;             // 0..NROWS-1
    const int b = row / NS, s = row - b * NS;
    const size_t base = (size_t)(b * (NS + 1) + s) * NV;
    const float4* __restrict__ x4 = (const float4*)(logits + base);
    const float4* __restrict__ y4 = (const float4*)(ref_logits + base);
    const int tid = threadIdx.x;

    float sx[4] = {0.f, 0.f, 0.f, 0.f};
    float sy[4] = {0.f, 0.f, 0.f, 0.f};
    float ty[4] = {0.f, 0.f, 0.f, 0.f};
    float mx = -INFINITY, my = -INFINITY;

    // NV/4 = 8000 float4 per row; 31 full iterations of 256 + tail of 64.
    // Depth-2 pipeline: buffers A,B hold iterations k and k+1; prefetch k+2/k+3
    // before consuming, so ~4KB per wave stays in flight.
    const int NIT = 31;                     // full iterations
    float4 xa = x4[tid],        ya = y4[tid];         // iter 0
    float4 xb = x4[tid + 256],  yb = y4[tid + 256];   // iter 1

    int k = 0;
    for (; k + 2 < NIT; k += 2) {
        float4 cx = xa, cy = ya;
        xa = x4[tid + (k + 2) * 256];                 // prefetch iter k+2
        ya = y4[tid + (k + 2) * 256];
        proc4(cx, cy, sx, sy, ty, mx, my);            // consume iter k
        cx = xb; cy = yb;
        if (k + 3 < NIT) {
            xb = x4[tid + (k + 3) * 256];             // prefetch iter k+3
            yb = y4[tid + (k + 3) * 256];
        }
        proc4(cx, cy, sx, sy, ty, mx, my);            // consume iter k+1
    }
    // drain: NIT=31 (odd) -> after loop (k==30), iter 30 sits in A
    proc4(xa, ya, sx, sy, ty, mx, my);
    // tail: float4 indices 7936..7999 (64 of them)
    if (tid < 64) {
        float4 cx = x4[7936 + tid];
        float4 cy = y4[7936 + tid];
        proc4(cx, cy, sx, sy, ty, mx, my);
    }

    float Sx = (sx[0] + sx[1]) + (sx[2] + sx[3]);
    float Sy = (sy[0] + sy[1]) + (sy[2] + sy[3]);
    float Ty = (ty[0] + ty[1]) + (ty[2] + ty[3]);

    // wave butterfly reduce (64 lanes)
    for (int off = 32; off > 0; off >>= 1) {
        Sx += __shfl_xor(Sx, off);
        Sy += __shfl_xor(Sy, off);
        Ty += __shfl_xor(Ty, off);
        mx = fmaxf(mx, __shfl_xor(mx, off));
        my = fmaxf(my, __shfl_xor(my, off));
    }
    __shared__ float red[4][5];
    const int wave = tid >> 6, lane = tid & 63;
    if (lane == 0) {
        red[wave][0] = Sx; red[wave][1] = Sy; red[wave][2] = Ty;
        red[wave][3] = mx; red[wave][4] = my;
    }
    __syncthreads();
    float tSx = 0.f, tSy = 0.f, tTy = 0.f, tMx = -INFINITY, tMy = -INFINITY;
#pragma unroll
    for (int w = 0; w < 4; ++w) {
        tSx += red[w][0];
        tSy += red[w][1];
        tTy += red[w][2];
        tMx = fmaxf(tMx, red[w][3]);
        tMy = fmaxf(tMy, red[w][4]);
    }

    float lzx, lzy, klv;
    if (tMx < SAFE_MAX && tMy < SAFE_MAX) {
        lzx = __logf(tSx);
        lzy = __logf(tSy);
        klv = tTy / tSy + lzx - lzy;
    } else {
        // rare fallback: max-shifted second pass (data is cache-warm)
        float fsx = 0.f, fsy = 0.f, fty = 0.f;
        for (int i = tid; i < NV / 4; i += 256) {
            float4 xv = x4[i];
            float4 yv = y4[i];
            float xs2[4] = {xv.x, xv.y, xv.z, xv.w};
            float ys2[4] = {yv.x, yv.y, yv.z, yv.w};
#pragma unroll
            for (int j = 0; j < 4; ++j) {
                float xe = xs2[j], ye = ys2[j];
                fsx += __expf(xe - tMx);
                float ey = __expf(ye - tMy);
                fsy += ey;
                fty = fmaf(ey, ye - xe, fty);
            }
        }
        for (int off = 32; off > 0; off >>= 1) {
            fsx += __shfl_xor(fsx, off);
            fsy += __shfl_xor(fsy, off);
            fty += __shfl_xor(fty, off);
        }
        __syncthreads();
        if (lane == 0) { red[wave][0] = fsx; red[wave][1] = fsy; red[wave][2] = fty; }
        __syncthreads();
        float gSx = 0.f, gSy = 0.f, gTy = 0.f;
#pragma unroll
        for (int w = 0; w < 4; ++w) { gSx += red[w][0]; gSy += red[w][1]; gTy += red[w][2]; }
        lzx = tMx + __logf(gSx);
        lzy = tMy + __logf(gSy);
        klv = gTy / gSy + lzx - lzy;
    }

    if (tid == 0) {
        logZx[row] = lzx;
        logZy[row] = lzy;
        klrow[row] = klv;
        int id0 = input_ids[b * NS + s];
        surp[row] = lzx - logits[base + id0];
        if (s < NS - 1) {
            int id1 = input_ids[b * NS + s + 1];
            gval[row]  = logits[base + id1] - lzx;
            grval[row] = ref_logits[base + id1] - lzy;
        } else {
            gval[row] = 0.f;
            grval[row] = 0.f;
        }
    }
}

// Kernel B: single block finalize — scatter-add summed_surprisal, preds, all scalars.
__global__ __launch_bounds__(1024) void kfinal(const int* __restrict__ input_ids,
                                               const int* __restrict__ attention_mask,
                                               const int* __restrict__ word_ids,
                                               const int* __restrict__ word_lengths,
                                               const float* __restrict__ lufreq,
                                               const float* __restrict__ labels,
                                               const float* __restrict__ W_head,
                                               const float* __restrict__ b_head,
                                               const float* __restrict__ logZx,
                                               const float* __restrict__ logZy,
                                               const float* __restrict__ klrow,
                                               const float* __restrict__ surp,
                                               const float* __restrict__ gval,
                                               const float* __restrict__ grval,
                                               float* __restrict__ out) {
    __shared__ float summed[NROWS];   // 8 KB: summed_surprisal (B,S)
    const int tid = threadIdx.x;
    for (int p = tid; p < NROWS; p += 1024) summed[p] = 0.f;
    __syncthreads();
    for (int p = tid; p < NROWS; p += 1024) {
        int b = p / NS;
        int wid = word_ids[p];
        if (wid >= 0 && wid < NS) atomicAdd(&summed[b * NS + wid], surp[p]);
    }
    __syncthreads();

    const float W0 = W_head[0], W1 = W_head[1], W2 = W_head[2], bh = b_head[0];
    float mse_n = 0.f, mse_d = 0.f, kl_n = 0.f, kl_d = 0.f;
    float g_n = 0.f, gr_n = 0.f, g_d = 0.f;
    for (int p = tid; p < NROWS; p += 1024) {
        int b = p / NS, s = p - b * NS;
        int wid = word_ids[p];
        bool valid = (wid >= 0) && (wid < NS);
        int safe = wid < 0 ? 0 : (wid > NS - 1 ? NS - 1 : wid);
        int lens = word_lengths[b * NS + safe];
        valid = valid && (lens != -1);
        float el = valid ? (float)lens : 0.f;
        float ef = valid ? lufreq[b * NS + safe] : 0.f;
        float pred = summed[p] * W0 + el * W1 + ef * W2 + bh;
        out[1 + p] = pred;
        float lab = labels[p];
        float mw = (lab != -1.0f) ? 1.f : 0.f;
        float diff = lab - pred;
        mse_n += diff * diff * mw;
        mse_d += mw;
        float km = (s == 0) ? 0.f : ((word_ids[p - 1] != -1) ? 1.f : 0.f);
        kl_n += klrow[p] * km;
        kl_d += km;
        if (s < NS - 1) {
            float am = (float)attention_mask[b * NS + s + 1];
            g_n += gval[p] * am;
            gr_n += grval[p] * am;
            g_d += am;
        }
    }
    for (int off = 32; off > 0; off >>= 1) {
        mse_n += __shfl_xor(mse_n, off);
        mse_d += __shfl_xor(mse_d, off);
        kl_n  += __shfl_xor(kl_n, off);
        kl_d  += __shfl_xor(kl_d, off);
        g_n   += __shfl_xor(g_n, off);
        gr_n  += __shfl_xor(gr_n, off);
        g_d   += __shfl_xor(g_d, off);
    }
    __shared__ float r2[16][7];
    const int wave = tid >> 6, lane = tid & 63;
    if (lane == 0) {
        r2[wave][0] = mse_n; r2[wave][1] = mse_d;
        r2[wave][2] = kl_n;  r2[wave][3] = kl_d;
        r2[wave][4] = g_n;   r2[wave][5] = gr_n; r2[wave][6] = g_d;
    }
    __syncthreads();
    if (tid == 0) {
        float a0 = 0, a1 = 0, a2 = 0, a3 = 0, a4 = 0, a5 = 0, a6 = 0;
        for (int w = 0; w < 16; ++w) {
            a0 += r2[w][0]; a1 += r2[w][1]; a2 += r2[w][2]; a3 += r2[w][3];
            a4 += r2[w][4]; a5 += r2[w][5]; a6 += r2[w][6];
        }
        float mse = a0 / a1;
        float kl = a2 / a3;
        float loss = mse + KL_ALPHA * kl;   // MSE_WEIGHT = 1
        float avg = a4 / a6;
        float delta = avg - a5 / a6;
        out[0] = loss;
        out[1 + NROWS] = mse;
        out[2 + NROWS] = kl;
        out[3 + NROWS] = avg;
        out[4 + NROWS] = delta;
    }
}

extern "C" void kernel_launch(void* const* d_in, const int* in_sizes, int n_in,
                              void* d_out, int out_size, void* d_ws, size_t ws_size,
                              hipStream_t stream) {
    const float* logits        = (const float*)d_in[0];
    const float* ref_logits    = (const float*)d_in[1];
    const int*   input_ids     = (const int*)d_in[2];
    const int*   attention_mask= (const int*)d_in[3];
    const int*   word_ids      = (const int*)d_in[4];
    const int*   word_lengths  = (const int*)d_in[5];
    const float* lufreq        = (const float*)d_in[6];
    const float* labels        = (const float*)d_in[7];
    const float* W_head        = (const float*)d_in[8];
    const float* b_head        = (const float*)d_in[9];
    float* out = (float*)d_out;
    float* ws = (float*)d_ws;

    float* logZx = ws;
    float* logZy = ws + NROWS;
    float* klrow = ws + 2 * NROWS;
    float* surp  = ws + 3 * NROWS;
    float* gvals = ws + 4 * NROWS;
    float* grvals= ws + 5 * NROWS;

    hipLaunchKernelGGL(krow, dim3(NROWS), dim3(256), 0, stream,
                       logits, ref_logits, input_ids,
                       logZx, logZy, klrow, surp, gvals, grvals);
    hipLaunchKernelGGL(kfinal, dim3(1), dim3(1024), 0, stream,
                       input_ids, attention_mask, word_ids, word_lengths,
                       lufreq, labels, W_head, b_head,
                       logZx, logZy, klrow, surp, gvals, grvals, out);
}

// Round 4
// 105.925 us; speedup vs baseline: 1.0547x; 1.0191x over previous
//
#include <hip/hip_runtime.h>
#include <math.h>

#define NB 4
#define NS 512
#define NV 32000
#define NROWS (NB * NS)
#define KL_ALPHA 0.3f
#define NIT 31   /* full 256-thread iterations per row; tail of 64 float4 */

// per-element accumulation: sums of exp(x), exp(y), exp(y)*(y-x)
__device__ __forceinline__ void proc4(const float4& xv, const float4& yv,
                                      float* __restrict__ sx, float* __restrict__ sy,
                                      float* __restrict__ ty) {
    float xs[4] = {xv.x, xv.y, xv.z, xv.w};
    float ys[4] = {yv.x, yv.y, yv.z, yv.w};
#pragma unroll
    for (int j = 0; j < 4; ++j) {
        float xe = xs[j], ye = ys[j];
        float ex = __expf(xe);
        float ey = __expf(ye);
        sx[j] += ex;
        sy[j] += ey;
        ty[j] = fmaf(ey, ye - xe, ty[j]);
    }
}

// Kernel A: per-row (b,s) softmax stats for logits (x) and ref_logits (y).
// One block per row. Depth-4 register pipeline, pinned with sched_barrier so
// the compiler cannot sink the prefetch loads (R2's depth-2 got flattened).
__global__ __launch_bounds__(256) void krow(const float* __restrict__ logits,
                                            const float* __restrict__ ref_logits,
                                            const int* __restrict__ input_ids,
                                            float* __restrict__ logZx,
                                            float* __restrict__ logZy,
                                            float* __restrict__ klrow,
                                            float* __restrict__ surp,
                                            float* __restrict__ gval,
                                            float* __restrict__ grval) {
    const int row = blockIdx.x;             // 0..NROWS-1
    const int b = row / NS, s = row - b * NS;
    const size_t base = (size_t)(b * (NS + 1) + s) * NV;
    const float4* __restrict__ x4 = (const float4*)(logits + base);
    const float4* __restrict__ y4 = (const float4*)(ref_logits + base);
    const int tid = threadIdx.x;

    float sx[4] = {0.f, 0.f, 0.f, 0.f};
    float sy[4] = {0.f, 0.f, 0.f, 0.f};
    float ty[4] = {0.f, 0.f, 0.f, 0.f};

    // tail first (indices 7936..7999), single latency hit amortized over the row
    if (tid < 64) {
        proc4(x4[7936 + tid], y4[7936 + tid], sx, sy, ty);
    }

    // depth-4 pinned pipeline over the 31 full iterations
    float4 bx[4], by[4];
#pragma unroll
    for (int k = 0; k < 4; ++k) {
        bx[k] = x4[tid + k * 256];
        by[k] = y4[tid + k * 256];
    }
    __builtin_amdgcn_sched_barrier(0);
#pragma unroll
    for (int k = 0; k < NIT; ++k) {
        proc4(bx[k & 3], by[k & 3], sx, sy, ty);
        if (k + 4 < NIT) {
            bx[k & 3] = x4[tid + (k + 4) * 256];
            by[k & 3] = y4[tid + (k + 4) * 256];
        }
        __builtin_amdgcn_sched_barrier(0);   // loads for k+4 may not sink below here
    }

    float Sx = (sx[0] + sx[1]) + (sx[2] + sx[3]);
    float Sy = (sy[0] + sy[1]) + (sy[2] + sy[3]);
    float Ty = (ty[0] + ty[1]) + (ty[2] + ty[3]);

    // wave butterfly reduce (64 lanes)
    for (int off = 32; off > 0; off >>= 1) {
        Sx += __shfl_xor(Sx, off);
        Sy += __shfl_xor(Sy, off);
        Ty += __shfl_xor(Ty, off);
    }
    __shared__ float red[4][5];
    const int wave = tid >> 6, lane = tid & 63;
    if (lane == 0) {
        red[wave][0] = Sx; red[wave][1] = Sy; red[wave][2] = Ty;
    }
    __syncthreads();
    float tSx = 0.f, tSy = 0.f, tTy = 0.f;
#pragma unroll
    for (int w = 0; w < 4; ++w) {
        tSx += red[w][0];
        tSy += red[w][1];
        tTy += red[w][2];
    }

    // guard: direct exp-sum is valid unless it overflowed (inf/nan) or fully
    // underflowed (0). For N(0,1)-scale data this never triggers.
    bool bad = !(tSx > 1e-35f) || !(tSy > 1e-35f) ||
               isinf(tSx) || isinf(tSy) || isinf(tTy) || isnan(tTy);

    float lzx, lzy, klv;
    if (!bad) {
        lzx = __logf(tSx);
        lzy = __logf(tSy);
        klv = tTy / tSy + lzx - lzy;
    } else {
        // rare fallback: max pass + shifted second pass (data is cache-warm)
        float mx = -INFINITY, my = -INFINITY;
        for (int i = tid; i < NV / 4; i += 256) {
            float4 xv = x4[i];
            float4 yv = y4[i];
            mx = fmaxf(mx, fmaxf(fmaxf(xv.x, xv.y), fmaxf(xv.z, xv.w)));
            my = fmaxf(my, fmaxf(fmaxf(yv.x, yv.y), fmaxf(yv.z, yv.w)));
        }
        for (int off = 32; off > 0; off >>= 1) {
            mx = fmaxf(mx, __shfl_xor(mx, off));
            my = fmaxf(my, __shfl_xor(my, off));
        }
        __syncthreads();
        if (lane == 0) { red[wave][0] = mx; red[wave][1] = my; }
        __syncthreads();
        float tMx = -INFINITY, tMy = -INFINITY;
#pragma unroll
        for (int w = 0; w < 4; ++w) {
            tMx = fmaxf(tMx, red[w][0]);
            tMy = fmaxf(tMy, red[w][1]);
        }
        float fsx = 0.f, fsy = 0.f, fty = 0.f;
        for (int i = tid; i < NV / 4; i += 256) {
            float4 xv = x4[i];
            float4 yv = y4[i];
            float xs2[4] = {xv.x, xv.y, xv.z, xv.w};
            float ys2[4] = {yv.x, yv.y, yv.z, yv.w};
#pragma unroll
            for (int j = 0; j < 4; ++j) {
                float xe = xs2[j], ye = ys2[j];
                fsx += __expf(xe - tMx);
                float ey = __expf(ye - tMy);
                fsy += ey;
                fty = fmaf(ey, ye - xe, fty);
            }
        }
        for (int off = 32; off > 0; off >>= 1) {
            fsx += __shfl_xor(fsx, off);
            fsy += __shfl_xor(fsy, off);
            fty += __shfl_xor(fty, off);
        }
        __syncthreads();
        if (lane == 0) { red[wave][0] = fsx; red[wave][1] = fsy; red[wave][2] = fty; }
        __syncthreads();
        float gSx = 0.f, gSy = 0.f, gTy = 0.f;
#pragma unroll
        for (int w = 0; w < 4; ++w) { gSx += red[w][0]; gSy += red[w][1]; gTy += red[w][2]; }
        lzx = tMx + __logf(gSx);
        lzy = tMy + __logf(gSy);
        klv = gTy / gSy + lzx - lzy;
    }

    if (tid == 0) {
        logZx[row] = lzx;
        logZy[row] = lzy;
        klrow[row] = klv;
        int id0 = input_ids[b * NS + s];
        surp[row] = lzx - logits[base + id0];
        if (s < NS - 1) {
            int id1 = input_ids[b * NS + s + 1];
            gval[row]  = logits[base + id1] - lzx;
            grval[row] = ref_logits[base + id1] - lzy;
        } else {
            gval[row] = 0.f;
            grval[row] = 0.f;
        }
    }
}

// Kernel B: single block finalize — scatter-add summed_surprisal, preds, all scalars.
__global__ __launch_bounds__(1024) void kfinal(const int* __restrict__ input_ids,
                                               const int* __restrict__ attention_mask,
                                               const int* __restrict__ word_ids,
                                               const int* __restrict__ word_lengths,
                                               const float* __restrict__ lufreq,
                                               const float* __restrict__ labels,
                                               const float* __restrict__ W_head,
                                               const float* __restrict__ b_head,
                                               const float* __restrict__ logZx,
                                               const float* __restrict__ logZy,
                                               const float* __restrict__ klrow,
                                               const float* __restrict__ surp,
                                               const float* __restrict__ gval,
                                               const float* __restrict__ grval,
                                               float* __restrict__ out) {
    __shared__ float summed[NROWS];   // 8 KB: summed_surprisal (B,S)
    const int tid = threadIdx.x;
    for (int p = tid; p < NROWS; p += 1024) summed[p] = 0.f;
    __syncthreads();
    for (int p = tid; p < NROWS; p += 1024) {
        int b = p / NS;
        int wid = word_ids[p];
        if (wid >= 0 && wid < NS) atomicAdd(&summed[b * NS + wid], surp[p]);
    }
    __syncthreads();

    const float W0 = W_head[0], W1 = W_head[1], W2 = W_head[2], bh = b_head[0];
    float mse_n = 0.f, mse_d = 0.f, kl_n = 0.f, kl_d = 0.f;
    float g_n = 0.f, gr_n = 0.f, g_d = 0.f;
    for (int p = tid; p < NROWS; p += 1024) {
        int b = p / NS, s = p - b * NS;
        int wid = word_ids[p];
        bool valid = (wid >= 0) && (wid < NS);
        int safe = wid < 0 ? 0 : (wid > NS - 1 ? NS - 1 : wid);
        int lens = word_lengths[b * NS + safe];
        valid = valid && (lens != -1);
        float el = valid ? (float)lens : 0.f;
        float ef = valid ? lufreq[b * NS + safe] : 0.f;
        float pred = summed[p] * W0 + el * W1 + ef * W2 + bh;
        out[1 + p] = pred;
        float lab = labels[p];
        float mw = (lab != -1.0f) ? 1.f : 0.f;
        float diff = lab - pred;
        mse_n += diff * diff * mw;
        mse_d += mw;
        float km = (s == 0) ? 0.f : ((word_ids[p - 1] != -1) ? 1.f : 0.f);
        kl_n += klrow[p] * km;
        kl_d += km;
        if (s < NS - 1) {
            float am = (float)attention_mask[b * NS + s + 1];
            g_n += gval[p] * am;
            gr_n += grval[p] * am;
            g_d += am;
        }
    }
    for (int off = 32; off > 0; off >>= 1) {
        mse_n += __shfl_xor(mse_n, off);
        mse_d += __shfl_xor(mse_d, off);
        kl_n  += __shfl_xor(kl_n, off);
        kl_d  += __shfl_xor(kl_d, off);
        g_n   += __shfl_xor(g_n, off);
        gr_n  += __shfl_xor(gr_n, off);
        g_d   += __shfl_xor(g_d, off);
    }
    __shared__ float r2[16][7];
    const int wave = tid >> 6, lane = tid & 63;
    if (lane == 0) {
        r2[wave][0] = mse_n; r2[wave][1] = mse_d;
        r2[wave][2] = kl_n;  r2[wave][3] = kl_d;
        r2[wave][4] = g_n;   r2[wave][5] = gr_n; r2[wave][6] = g_d;
    }
    __syncthreads();
    if (tid == 0) {
        float a0 = 0, a1 = 0, a2 = 0, a3 = 0, a4 = 0, a5 = 0, a6 = 0;
        for (int w = 0; w < 16; ++w) {
            a0 += r2[w][0]; a1 += r2[w][1]; a2 += r2[w][2]; a3 += r2[w][3];
            a4 += r2[w][4]; a5 += r2[w][5]; a6 += r2[w][6];
        }
        float mse = a0 / a1;
        float kl = a2 / a3;
        float loss = mse + KL_ALPHA * kl;   // MSE_WEIGHT = 1
        float avg = a4 / a6;
        float delta = avg - a5 / a6;
        out[0] = loss;
        out[1 + NROWS] = mse;
        out[2 + NROWS] = kl;
        out[3 + NROWS] = avg;
        out[4 + NROWS] = delta;
    }
}

extern "C" void kernel_launch(void* const* d_in, const int* in_sizes, int n_in,
                              void* d_out, int out_size, void* d_ws, size_t ws_size,
                              hipStream_t stream) {
    const float* logits        = (const float*)d_in[0];
    const float* ref_logits    = (const float*)d_in[1];
    const int*   input_ids     = (const int*)d_in[2];
    const int*   attention_mask= (const int*)d_in[3];
    const int*   word_ids      = (const int*)d_in[4];
    const int*   word_lengths  = (const int*)d_in[5];
    const float* lufreq        = (const float*)d_in[6];
    const float* labels        = (const float*)d_in[7];
    const float* W_head        = (const float*)d_in[8];
    const float* b_head        = (const float*)d_in[9];
    float* out = (float*)d_out;
    float* ws = (float*)d_ws;

    float* logZx = ws;
    float* logZy = ws + NROWS;
    float* klrow = ws + 2 * NROWS;
    float* surp  = ws + 3 * NROWS;
    float* gvals = ws + 4 * NROWS;
    float* grvals= ws + 5 * NROWS;

    hipLaunchKernelGGL(krow, dim3(NROWS), dim3(256), 0, stream,
                       logits, ref_logits, input_ids,
                       logZx, logZy, klrow, surp, gvals, grvals);
    hipLaunchKernelGGL(kfinal, dim3(1), dim3(1024), 0, stream,
                       input_ids, attention_mask, word_ids, word_lengths,
                       lufreq, labels, W_head, b_head,
                       logZx, logZy, klrow, surp, gvals, grvals, out);
}